// Round 6
// baseline (527.395 us; speedup 1.0000x reference)
//
#include <hip/hip_runtime.h>
#include <math.h>

// AdaptivePatchEmbedding — MI355X, round 6.
// r5 deduction: router (~215us) AND embed (~215us) both slow; r4 counters
// show 95% memory-stall at ~1 block/CU residency. This round: one block per
// row (4096 blocks): LDS-staged x row, wave-parallel router (shfl_xor tree),
// 84 KB contiguous streaming per block, PLAIN stores (drop nt — fillBuffer
// hits 6.3 TB/s with plain stores; nt suspected of defeating write-combine).
//
// Output layout (float, reference return order):
//   [0 .. XP_ELEMS)                 x_patch [4096, 42, 512]
//   [XP_ELEMS]                      C = 32
//   [XP_ELEMS+1 ..]                 cls_pred (region-major: r*NROWS + n)

namespace {
constexpr int NROWS = 4096;   // B*C
constexpr int SEQ   = 336;
constexpr int RREG  = 7;
constexpr int TGT   = 6;
constexpr int DM    = 512;
constexpr int DM4   = DM / 4;
constexpr int NEXP  = 4;
constexpr long long XP_ELEMS = (long long)NROWS * RREG * TGT * DM; // 88,080,384
constexpr int PE_ELEMS = RREG * TGT * DM;                          // 21504
}

typedef float v4f __attribute__((ext_vector_type(4)));

// Positional embedding in double, matching numpy float64 -> float32.
__global__ void pe_kernel(float* __restrict__ pe) {
    int i = blockIdx.x * blockDim.x + threadIdx.x;
    if (i >= PE_ELEMS) return;
    int p = i / DM, d = i - p * DM;
    int j = d >> 1;
    double div = exp((double)(2 * j) * -(log(10000.0) / (double)DM));
    double a = (double)p * div;
    pe[i] = (d & 1) ? (float)cos(a) : (float)sin(a);
}

// fp32 fallback pos-emb (only if ws too small for the table).
__device__ inline float pe_val(int p, int d) {
    int j = d >> 1;
    float div = __expf((float)(2 * j) * (-9.210340371976184f / 512.0f));
    float a = (float)p * div;
    return (d & 1) ? __cosf(a) : __sinf(a);
}

template <bool HAVE_PE>
__global__ __launch_bounds__(256) void fused_kernel(
    const float* __restrict__ x,   const float* __restrict__ un,
    const float* __restrict__ W1,  const float* __restrict__ b1,
    const float* __restrict__ W2,  const float* __restrict__ b2,
    const float* __restrict__ We0, const float* __restrict__ We1,
    const float* __restrict__ We2, const float* __restrict__ We3,
    const float* __restrict__ pe,  float* __restrict__ out)
{
    const int n    = blockIdx.x;          // row in [0, 4096)
    const int tid  = threadIdx.x;
    const int lane = tid & 63;
    const int wave = tid >> 6;

    __shared__ float s_x[SEQ];
    __shared__ float s_w[RREG];
    __shared__ int   s_e[RREG];

    // ---- stage the full x row (336 floats) into LDS ----
    s_x[tid] = x[(size_t)n * SEQ + tid];
    if (tid < SEQ - 256) s_x[256 + tid] = x[(size_t)n * SEQ + 256 + tid];
    __syncthreads();

    // ---- router: wave w handles regions r = 2w, 2w+1 (r<7) ----
    #pragma unroll
    for (int rr = 0; rr < 2; ++rr) {
        const int r = wave * 2 + rr;
        if (r < RREG) {
            const float* sx = &s_x[r * 48];
            // lane j computes hidden unit h_j (W1 reads coalesced across lanes)
            float h = b1[lane];
            #pragma unroll
            for (int k = 0; k < 48; ++k) h = fmaf(sx[k], W1[k * 64 + lane], h);
            h = fmaxf(h, 0.0f);
            float p0 = h * W2[lane * NEXP + 0];
            float p1 = h * W2[lane * NEXP + 1];
            float p2 = h * W2[lane * NEXP + 2];
            float p3 = h * W2[lane * NEXP + 3];
            #pragma unroll
            for (int m = 1; m < 64; m <<= 1) {
                p0 += __shfl_xor(p0, m);
                p1 += __shfl_xor(p1, m);
                p2 += __shfl_xor(p2, m);
                p3 += __shfl_xor(p3, m);
            }
            if (lane == 0) {
                const int g = n * RREG + r;
                const float* ug = un + (size_t)g * NEXP;
                float z0 = (b2[0] + p0 + -logf(-logf(ug[0] + 1e-10f) + 1e-10f)) / 0.5f;
                float z1 = (b2[1] + p1 + -logf(-logf(ug[1] + 1e-10f) + 1e-10f)) / 0.5f;
                float z2 = (b2[2] + p2 + -logf(-logf(ug[2] + 1e-10f) + 1e-10f)) / 0.5f;
                float z3 = (b2[3] + p3 + -logf(-logf(ug[3] + 1e-10f) + 1e-10f)) / 0.5f;
                int e = 0; float zm = z0;
                if (z1 > zm) { zm = z1; e = 1; }
                if (z2 > zm) { zm = z2; e = 2; }
                if (z3 > zm) { zm = z3; e = 3; }
                float s = 1.0f /
                    (((expf(z0 - zm) + expf(z1 - zm)) + expf(z2 - zm)) + expf(z3 - zm));
                s_w[r] = (1.0f + s) - s;
                s_e[r] = e;
                out[(size_t)XP_ELEMS + 1 + (size_t)r * NROWS + n] = (float)e; // cls_pred
            }
        }
    }
    if (n == 0 && tid == 0) out[(size_t)XP_ELEMS] = 32.0f;                    // C
    __syncthreads();

    // ---- streaming embed: 7 regions x 12 KB contiguous, plain stores ----
    const int c4   = tid & 127;   // vec4 column within a row
    const int half = tid >> 7;    // 0: rows {0,2,4}; 1: rows {1,3,5}
    v4f* __restrict__ outv = reinterpret_cast<v4f*>(out);
    const v4f* __restrict__ pev = reinterpret_cast<const v4f*>(pe);

    for (int r = 0; r < RREG; ++r) {
        const float w = s_w[r];
        const int   e = s_e[r];              // uniform -> no divergence
        const float* sx = &s_x[r * 48];
        const size_t ob = ((size_t)n * (RREG * TGT) + (size_t)r * TGT) * DM4;
        const int pb = r * TGT * DM4;

        auto pe4 = [&](int t) -> v4f {
            if constexpr (HAVE_PE) {
                return pev[pb + t * DM4 + c4];
            } else {
                v4f v;
                v.x = pe_val(r * TGT + t, 4 * c4 + 0);
                v.y = pe_val(r * TGT + t, 4 * c4 + 1);
                v.z = pe_val(r * TGT + t, 4 * c4 + 2);
                v.w = pe_val(r * TGT + t, 4 * c4 + 3);
                return v;
            }
        };
        auto emit = [&](int t, const v4f& a) {
            v4f pv = pe4(t);
            v4f v;
            v.x = fmaf(a.x, w, pv.x);
            v.y = fmaf(a.y, w, pv.y);
            v.z = fmaf(a.z, w, pv.z);
            v.w = fmaf(a.w, w, pv.w);
            outv[ob + (size_t)t * DM4 + c4] = v;   // plain streaming store
        };
        auto fma4 = [](float xv, const v4f& wv, v4f& a) {
            a.x = fmaf(xv, wv.x, a.x);
            a.y = fmaf(xv, wv.y, a.y);
            a.z = fmaf(xv, wv.z, a.z);
            a.w = fmaf(xv, wv.w, a.w);
        };
        const v4f zero4 = (v4f)(0.0f);

        if (e == 0) {
            // plen=8: patch map t->t; this thread's rows t = half + 2*i
            const v4f* W = reinterpret_cast<const v4f*>(We0);
            v4f a0 = zero4, a1 = zero4, a2 = zero4;
            #pragma unroll
            for (int k = 0; k < 8; ++k) {
                v4f wv = W[k * DM4 + c4];
                fma4(sx[(half + 0) * 8 + k], wv, a0);
                fma4(sx[(half + 2) * 8 + k], wv, a1);
                fma4(sx[(half + 4) * 8 + k], wv, a2);
            }
            emit(half + 0, a0);
            emit(half + 2, a1);
            emit(half + 4, a2);
        } else if (e == 1) {
            // plen=16: patch map [0,0,0,0,1,1]
            const v4f* W = reinterpret_cast<const v4f*>(We1);
            v4f a0 = zero4, a1 = zero4;
            #pragma unroll
            for (int k = 0; k < 16; ++k) {
                v4f wv = W[k * DM4 + c4];
                fma4(sx[k],      wv, a0);
                fma4(sx[16 + k], wv, a1);
            }
            #pragma unroll
            for (int i = 0; i < 3; ++i) {
                int t = half + 2 * i;
                emit(t, (t < 4) ? a0 : a1);
            }
        } else if (e == 2) {
            // plen=24: patch map [0,0,0,0,0,1]
            const v4f* W = reinterpret_cast<const v4f*>(We2);
            v4f a0 = zero4, a1 = zero4;
            #pragma unroll
            for (int k = 0; k < 24; ++k) {
                v4f wv = W[k * DM4 + c4];
                fma4(sx[k],      wv, a0);
                fma4(sx[24 + k], wv, a1);
            }
            #pragma unroll
            for (int i = 0; i < 3; ++i) {
                int t = half + 2 * i;
                emit(t, (t < 5) ? a0 : a1);
            }
        } else {
            // plen=48: single distinct patch
            const v4f* W = reinterpret_cast<const v4f*>(We3);
            v4f a0 = zero4;
            #pragma unroll
            for (int k = 0; k < 48; ++k) {
                v4f wv = W[k * DM4 + c4];
                fma4(sx[k], wv, a0);
            }
            #pragma unroll
            for (int i = 0; i < 3; ++i) emit(half + 2 * i, a0);
        }
    }
}

extern "C" void kernel_launch(void* const* d_in, const int* in_sizes, int n_in,
                              void* d_out, int out_size, void* d_ws, size_t ws_size,
                              hipStream_t stream) {
    const float* x   = (const float*)d_in[0];
    const float* un  = (const float*)d_in[1];
    const float* W1  = (const float*)d_in[2];
    const float* b1  = (const float*)d_in[3];
    const float* W2  = (const float*)d_in[4];
    const float* b2  = (const float*)d_in[5];
    const float* We0 = (const float*)d_in[6];
    const float* We1 = (const float*)d_in[7];
    const float* We2 = (const float*)d_in[8];
    const float* We3 = (const float*)d_in[9];
    float* out = (float*)d_out;

    if (ws_size >= (size_t)PE_ELEMS * sizeof(float)) {
        float* pe = (float*)d_ws;
        pe_kernel<<<(PE_ELEMS + 255) / 256, 256, 0, stream>>>(pe);
        fused_kernel<true><<<NROWS, 256, 0, stream>>>(
            x, un, W1, b1, W2, b2, We0, We1, We2, We3, pe, out);
    } else {
        fused_kernel<false><<<NROWS, 256, 0, stream>>>(
            x, un, W1, b1, W2, b2, We0, We1, We2, We3, (const float*)nullptr, out);
    }
}

// Round 8
// 439.361 us; speedup vs baseline: 1.2004x; 1.2004x over previous
//
#include <hip/hip_runtime.h>
#include <math.h>

// AdaptivePatchEmbedding — MI355X, round 8 (verbatim resubmit of r7; r7 never
// ran: GPU acquisition timeout).
// r6 counters: 238us, 1.45 TB/s writes, VALU 20%, occ 10.7%, FETCH 4.5MB —
// latency-bound; ~5K cycles/region invariant across r4/r5/r6 structures.
// Diagnosis: dependent We/pe loads between stores (L2 thrashed by the 345MB
// store stream; L3 absorbs -> low FETCH but ~600cy per load).
// Fix: load-free store loop. 512-thread blocks, thread = scalar column d:
//   - all 4 experts' weight columns in REGISTERS (96 floats, unrolled idx)
//   - pe table in LDS (86KB, staged once)
//   - x via uniform scalar-pipe loads (broadcast)
//   - zero barriers / zero vector loads in the row loop; plain 4B stores
//     (64-lane wave => 256B contiguous per store instr; fillBuffer proves
//     store path alone reaches 6.3 TB/s at ~10% occupancy).
// Router unchanged from r5 (passed; arithmetically ~10us).
//
// Output layout (float, reference return order):
//   [0 .. XP_ELEMS)   x_patch [4096, 42, 512]
//   [XP_ELEMS]        C = 32
//   [XP_ELEMS+1 ..]   cls_pred (region-major: r*NROWS + n)
// ws: [0,21504) pe | [21504, +2*NREG) (w,e) pairs

namespace {
constexpr int NROWS = 4096;
constexpr int SEQ   = 336;
constexpr int RREG  = 7;
constexpr int TGT   = 6;
constexpr int DM    = 512;
constexpr int NEXP  = 4;
constexpr int NREG  = NROWS * RREG;                                // 28672
constexpr long long XP_ELEMS = (long long)NROWS * RREG * TGT * DM; // 88,080,384
constexpr int PE_ELEMS = RREG * TGT * DM;                          // 21504
constexpr size_t WS_FLOATS = (size_t)PE_ELEMS + (size_t)NREG * 2;
constexpr int ROWS = 16;                 // rows per embed block
constexpr int EMB_BLOCKS = NROWS / ROWS; // 256
}

typedef float v4f __attribute__((ext_vector_type(4)));
typedef float v2f __attribute__((ext_vector_type(2)));

// Positional embedding in double, matching numpy float64 -> float32.
__global__ void pe_kernel(float* __restrict__ pe) {
    int i = blockIdx.x * blockDim.x + threadIdx.x;
    if (i >= PE_ELEMS) return;
    int p = i / DM, d = i - p * DM;
    int j = d >> 1;
    double div = exp((double)(2 * j) * -(log(10000.0) / (double)DM));
    double a = (double)p * div;
    pe[i] = (d & 1) ? (float)cos(a) : (float)sin(a);
}

// fp32 fallback pos-emb (only for the no-ws fallback kernel).
__device__ inline float pe_val(int p, int d) {
    int j = d >> 1;
    float div = __expf((float)(2 * j) * (-9.210340371976184f / 512.0f));
    float a = (float)p * div;
    return (d & 1) ? __cosf(a) : __sinf(a);
}

// ---------------- router: one thread per region (r5, passed) ----------------
__global__ __launch_bounds__(256) void router_kernel(
    const float* __restrict__ x,  const float* __restrict__ un,
    const float* __restrict__ W1, const float* __restrict__ b1,
    const float* __restrict__ W2, const float* __restrict__ b2,
    v2f* __restrict__ ew, float* __restrict__ out)
{
    const int g = blockIdx.x * 256 + threadIdx.x;
    if (g >= NREG) return;
    const int n = g / RREG, r = g - n * RREG;

    float xv[48];
    const v4f* xr4 = reinterpret_cast<const v4f*>(x + (size_t)n * SEQ + r * 48);
    #pragma unroll
    for (int i = 0; i < 12; ++i) {
        v4f v = xr4[i];
        xv[4 * i + 0] = v.x; xv[4 * i + 1] = v.y;
        xv[4 * i + 2] = v.z; xv[4 * i + 3] = v.w;
    }

    float z0 = b2[0], z1 = b2[1], z2 = b2[2], z3 = b2[3];
    for (int j = 0; j < 64; ++j) {
        float h = b1[j];
        #pragma unroll
        for (int k = 0; k < 48; ++k) h = fmaf(xv[k], W1[k * 64 + j], h);
        h = fmaxf(h, 0.0f);
        z0 = fmaf(h, W2[j * NEXP + 0], z0);
        z1 = fmaf(h, W2[j * NEXP + 1], z1);
        z2 = fmaf(h, W2[j * NEXP + 2], z2);
        z3 = fmaf(h, W2[j * NEXP + 3], z3);
    }

    const float* ug = un + (size_t)g * NEXP;
    z0 = (z0 + -logf(-logf(ug[0] + 1e-10f) + 1e-10f)) / 0.5f;
    z1 = (z1 + -logf(-logf(ug[1] + 1e-10f) + 1e-10f)) / 0.5f;
    z2 = (z2 + -logf(-logf(ug[2] + 1e-10f) + 1e-10f)) / 0.5f;
    z3 = (z3 + -logf(-logf(ug[3] + 1e-10f) + 1e-10f)) / 0.5f;

    int e = 0; float zm = z0;
    if (z1 > zm) { zm = z1; e = 1; }
    if (z2 > zm) { zm = z2; e = 2; }
    if (z3 > zm) { zm = z3; e = 3; }
    float s = 1.0f / (((expf(z0 - zm) + expf(z1 - zm)) + expf(z2 - zm)) + expf(z3 - zm));
    float w = (1.0f + s) - s;

    v2f p; p.x = w; p.y = (float)e;
    ew[g] = p;
    out[(size_t)XP_ELEMS + 1 + (size_t)r * NROWS + n] = (float)e;  // cls_pred
    if (g == 0) out[(size_t)XP_ELEMS] = 32.0f;                      // C
}

// -------- embed: thread = scalar column; weights in regs, pe in LDS --------
__global__ __launch_bounds__(512) void embed2_kernel(
    const float* __restrict__ x,   const v2f* __restrict__ ew,
    const float* __restrict__ We0, const float* __restrict__ We1,
    const float* __restrict__ We2, const float* __restrict__ We3,
    const float* __restrict__ pe,  float* __restrict__ out)
{
    const int d  = threadIdx.x;            // scalar column in [0,512)
    const int n0 = blockIdx.x * ROWS;

    __shared__ float s_pe[PE_ELEMS];       // 86016 B
    for (int i = d; i < PE_ELEMS; i += 512) s_pe[i] = pe[i];

    // All four experts' weight columns -> registers (96 floats, static idx).
    float w0[8], w1[16], w2[24], w3[48];
    #pragma unroll
    for (int k = 0; k < 8;  ++k) w0[k] = We0[k * DM + d];
    #pragma unroll
    for (int k = 0; k < 16; ++k) w1[k] = We1[k * DM + d];
    #pragma unroll
    for (int k = 0; k < 24; ++k) w2[k] = We2[k * DM + d];
    #pragma unroll
    for (int k = 0; k < 48; ++k) w3[k] = We3[k * DM + d];
    __syncthreads();                       // s_pe ready; no barriers after this

    for (int ni = 0; ni < ROWS; ++ni) {
        const int n = n0 + ni;
        const float* __restrict__ xrow = x + (size_t)n * SEQ;  // uniform addrs

        for (int r = 0; r < RREG; ++r) {
            const v2f p = ew[(size_t)n * RREG + r];   // uniform broadcast
            const float w = p.x;
            const int   e = (int)p.y;                 // uniform -> no divergence
            const float* __restrict__ sx = xrow + r * 48;
            float xv[48];
            #pragma unroll
            for (int k = 0; k < 48; ++k) xv[k] = sx[k];  // uniform scalar loads

            const size_t ob = ((size_t)n * RREG + r) * TGT * DM + d;
            const int pb = r * TGT * DM + d;

            if (e == 0) {
                // plen=8: map t->t
                float a[6] = {0.f, 0.f, 0.f, 0.f, 0.f, 0.f};
                #pragma unroll
                for (int k = 0; k < 8; ++k) {
                    const float wv = w0[k];
                    #pragma unroll
                    for (int q = 0; q < 6; ++q) a[q] = fmaf(xv[q * 8 + k], wv, a[q]);
                }
                #pragma unroll
                for (int t = 0; t < 6; ++t)
                    out[ob + (size_t)t * DM] = fmaf(a[t], w, s_pe[pb + t * DM]);
            } else if (e == 1) {
                // plen=16: map [0,0,0,0,1,1]
                float a0 = 0.f, a1 = 0.f;
                #pragma unroll
                for (int k = 0; k < 16; ++k) {
                    const float wv = w1[k];
                    a0 = fmaf(xv[k],      wv, a0);
                    a1 = fmaf(xv[16 + k], wv, a1);
                }
                #pragma unroll
                for (int t = 0; t < 6; ++t)
                    out[ob + (size_t)t * DM] =
                        fmaf((t < 4) ? a0 : a1, w, s_pe[pb + t * DM]);
            } else if (e == 2) {
                // plen=24: map [0,0,0,0,0,1]
                float a0 = 0.f, a1 = 0.f;
                #pragma unroll
                for (int k = 0; k < 24; ++k) {
                    const float wv = w2[k];
                    a0 = fmaf(xv[k],      wv, a0);
                    a1 = fmaf(xv[24 + k], wv, a1);
                }
                #pragma unroll
                for (int t = 0; t < 6; ++t)
                    out[ob + (size_t)t * DM] =
                        fmaf((t < 5) ? a0 : a1, w, s_pe[pb + t * DM]);
            } else {
                // plen=48: single distinct patch
                float a0 = 0.f;
                #pragma unroll
                for (int k = 0; k < 48; ++k) a0 = fmaf(xv[k], w3[k], a0);
                #pragma unroll
                for (int t = 0; t < 6; ++t)
                    out[ob + (size_t)t * DM] = fmaf(a0, w, s_pe[pb + t * DM]);
            }
        }
    }
}

// ---------------- fallback: fused kernel (ws too small) ----------------
__global__ __launch_bounds__(256) void fused_fb_kernel(
    const float* __restrict__ x,   const float* __restrict__ un,
    const float* __restrict__ W1,  const float* __restrict__ b1,
    const float* __restrict__ W2,  const float* __restrict__ b2,
    const float* __restrict__ We0, const float* __restrict__ We1,
    const float* __restrict__ We2, const float* __restrict__ We3,
    float* __restrict__ out)
{
    const int blk = blockIdx.x;
    const int n = blk / RREG;
    const int r = blk - n * RREG;
    const int tid = threadIdx.x;

    __shared__ float sx[48];
    __shared__ float sh[64];
    __shared__ float sz[NEXP];
    __shared__ float s_w;
    __shared__ int   s_e;

    if (tid < 48) sx[tid] = x[(size_t)n * SEQ + r * 48 + tid];
    __syncthreads();
    if (tid < 64) {
        float h = b1[tid];
        #pragma unroll
        for (int k = 0; k < 48; ++k) h = fmaf(sx[k], W1[k * 64 + tid], h);
        sh[tid] = fmaxf(h, 0.0f);
    }
    __syncthreads();
    if (tid < NEXP) {
        float z = b2[tid];
        #pragma unroll
        for (int j = 0; j < 64; ++j) z = fmaf(sh[j], W2[j * NEXP + tid], z);
        float uu = un[(size_t)blk * NEXP + tid];
        float g = -logf(-logf(uu + 1e-10f) + 1e-10f);
        sz[tid] = (z + g) / 0.5f;
    }
    __syncthreads();
    if (tid == 0) {
        float z0 = sz[0], z1 = sz[1], z2 = sz[2], z3 = sz[3];
        int e = 0; float zm = z0;
        if (z1 > zm) { zm = z1; e = 1; }
        if (z2 > zm) { zm = z2; e = 2; }
        if (z3 > zm) { zm = z3; e = 3; }
        float s = 1.0f / (((expf(z0 - zm) + expf(z1 - zm)) + expf(z2 - zm)) + expf(z3 - zm));
        s_e = e; s_w = (1.0f + s) - s;
        out[(size_t)XP_ELEMS + 1 + (size_t)r * NROWS + n] = (float)e;
        if (blk == 0) out[(size_t)XP_ELEMS] = 32.0f;
    }
    __syncthreads();

    const int e = s_e;
    const float w = s_w;
    const int d = tid;
    // 256 threads each handle 2 scalar columns {d, d+256} for all 6 t-rows.
    for (int rep = 0; rep < 2; ++rep) {
        const int dd = d + rep * 256;
        const size_t ob = ((size_t)n * RREG + r) * TGT * DM + dd;
        float acc[6] = {0.f, 0.f, 0.f, 0.f, 0.f, 0.f};
        if (e == 0) {
            for (int k = 0; k < 8; ++k) {
                float wv = We0[k * DM + dd];
                #pragma unroll
                for (int q = 0; q < 6; ++q) acc[q] = fmaf(sx[q * 8 + k], wv, acc[q]);
            }
        } else if (e == 1) {
            for (int k = 0; k < 16; ++k) {
                float wv = We1[k * DM + dd];
                acc[0] = fmaf(sx[k], wv, acc[0]);
                acc[4] = fmaf(sx[16 + k], wv, acc[4]);
            }
            acc[1] = acc[2] = acc[3] = acc[0]; acc[5] = acc[4];
        } else if (e == 2) {
            for (int k = 0; k < 24; ++k) {
                float wv = We2[k * DM + dd];
                acc[0] = fmaf(sx[k], wv, acc[0]);
                acc[5] = fmaf(sx[24 + k], wv, acc[5]);
            }
            acc[1] = acc[2] = acc[3] = acc[4] = acc[0];
        } else {
            for (int k = 0; k < 48; ++k) {
                float wv = We3[k * DM + dd];
                acc[0] = fmaf(sx[k], wv, acc[0]);
            }
            acc[1] = acc[2] = acc[3] = acc[4] = acc[5] = acc[0];
        }
        #pragma unroll
        for (int t = 0; t < 6; ++t)
            out[ob + (size_t)t * DM] =
                fmaf(acc[t], w, pe_val(r * TGT + t, dd));
    }
}

extern "C" void kernel_launch(void* const* d_in, const int* in_sizes, int n_in,
                              void* d_out, int out_size, void* d_ws, size_t ws_size,
                              hipStream_t stream) {
    const float* x   = (const float*)d_in[0];
    const float* un  = (const float*)d_in[1];
    const float* W1  = (const float*)d_in[2];
    const float* b1  = (const float*)d_in[3];
    const float* W2  = (const float*)d_in[4];
    const float* b2  = (const float*)d_in[5];
    const float* We0 = (const float*)d_in[6];
    const float* We1 = (const float*)d_in[7];
    const float* We2 = (const float*)d_in[8];
    const float* We3 = (const float*)d_in[9];
    float* out = (float*)d_out;

    if (ws_size >= WS_FLOATS * sizeof(float)) {
        float* pe = (float*)d_ws;
        v2f* ew = reinterpret_cast<v2f*>((float*)d_ws + PE_ELEMS);
        pe_kernel<<<(PE_ELEMS + 255) / 256, 256, 0, stream>>>(pe);
        router_kernel<<<(NREG + 255) / 256, 256, 0, stream>>>(
            x, un, W1, b1, W2, b2, ew, out);
        embed2_kernel<<<EMB_BLOCKS, 512, 0, stream>>>(
            x, ew, We0, We1, We2, We3, pe, out);
    } else {
        fused_fb_kernel<<<NREG, 256, 0, stream>>>(
            x, un, W1, b1, W2, b2, We0, We1, We2, We3, out);
    }
}